// Round 5
// baseline (405.011 us; speedup 1.0000x reference)
//
#include <hip/hip_runtime.h>

// Problem constants (fixed by setup_inputs)
#define BB 2
#define CC 256
#define HH 100
#define WW 100
#define NROI 512
#define KDIM 12544   // 49*256
#define FC 1024

typedef _Float16 half_t;
typedef _Float16 f16x2 __attribute__((ext_vector_type(2)));
typedef _Float16 f16x8 __attribute__((ext_vector_type(8)));
typedef _Float16 f16x4 __attribute__((ext_vector_type(4)));
typedef float f32x4 __attribute__((ext_vector_type(4)));

// ---------------- feat (B,C,H,W) fp32 -> featT (B,H*W,C) fp16 ----------------
__global__ __launch_bounds__(256) void transpose_feat(const float* __restrict__ feat,
                                                      half_t* __restrict__ featT) {
  __shared__ float tile[32][33];
  int b = blockIdx.z;
  int hw0 = blockIdx.x * 32;
  int c0 = blockIdx.y * 32;
  int tx = threadIdx.x, ty = threadIdx.y;
  const float* fb = feat + (size_t)b * CC * (HH * WW);
#pragma unroll
  for (int i = 0; i < 4; i++) {
    int c = c0 + ty + i * 8;
    int hw = hw0 + tx;
    tile[ty + i * 8][tx] = (hw < HH * WW) ? fb[(size_t)c * (HH * WW) + hw] : 0.0f;
  }
  __syncthreads();
  half_t* ob = featT + (size_t)b * (HH * WW) * CC;
#pragma unroll
  for (int i = 0; i < 4; i++) {
    int hw = hw0 + ty + i * 8;
    int c = c0 + tx;
    if (hw < HH * WW) ob[(size_t)hw * CC + c] = (half_t)tile[tx][ty + i * 8];
  }
}

// ---------------- fp32 -> fp16 convert (w1, w2) ----------------
__global__ __launch_bounds__(256) void convert_f32_f16(const float* __restrict__ in,
                                                       half_t* __restrict__ out, int n) {
  int i4 = (blockIdx.x * 256 + threadIdx.x) * 4;
  if (i4 < n) {
    float4 v = *(const float4*)(in + i4);
    f16x4 o;
    o[0] = (half_t)v.x; o[1] = (half_t)v.y; o[2] = (half_t)v.z; o[3] = (half_t)v.w;
    *(f16x4*)(out + i4) = o;
  }
}

// ---------------- deformable PSROI pooling, one block (512 thr) per ROI ----------------
template <bool PASS2>
__global__ __launch_bounds__(512) void pool_kernel(const half_t* __restrict__ featT,
                                                   const float* __restrict__ rois,
                                                   const float* __restrict__ om,
                                                   half_t* __restrict__ xout,
                                                   float* __restrict__ out) {
  struct Corner { int idx; float w; };
  __shared__ Corner s_c[784 * 4];                     // 25088 B
  __shared__ float s_vld[784];                        //  3136 B
  __shared__ float s_scale[49];
  __shared__ float  s_outf[PASS2 ? KDIM : 1];         // 50176 B (PASS2)
  __shared__ half_t s_outh[PASS2 ? 1 : KDIM];         // 25088 B (PASS1)

  const int n = blockIdx.x;
  const int tid = threadIdx.x;
  const float* r = rois + n * 5;
  const int b = (int)r[0];
  const float rsw = rintf(r[1]) * 0.0625f - 0.5f;     // rintf = round-half-even = jnp.round
  const float rsh = rintf(r[2]) * 0.0625f - 0.5f;
  const float rew = (rintf(r[3]) + 1.0f) * 0.0625f - 0.5f;
  const float reh = (rintf(r[4]) + 1.0f) * 0.0625f - 0.5f;
  const float roi_w = fmaxf(rew - rsw, 0.1f);
  const float roi_h = fmaxf(reh - rsh, 0.1f);
  const float bin_h = roi_h / 7.0f, bin_w = roi_w / 7.0f;
  const float sub_h = bin_h * 0.25f, sub_w = bin_w * 0.25f;
  const half_t* fb = featT + (size_t)b * (HH * WW) * CC;

  // ---- phase 1: sample metadata ----
  for (int si = tid; si < 784; si += 512) {
    int p = si >> 4, s = si & 15;
    int ph = p / 7, pw = p - ph * 7;
    float tx = 0.0f, ty = 0.0f;
    if (PASS2) {
      tx = om[n * 147 + p] * 0.1f;          // part_h == ph (verified)
      ty = om[n * 147 + 49 + p] * 0.1f;
    }
    float h = (float)ph * bin_h + rsh + ty * roi_h + (float)(s >> 2) * sub_h;
    float w = (float)pw * bin_w + rsw + tx * roi_w + (float)(s & 3) * sub_w;
    bool valid = (w >= -0.5f) && (w <= (float)WW - 0.5f) &&
                 (h >= -0.5f) && (h <= (float)HH - 0.5f);
    float hc = fminf(fmaxf(h, 0.0f), (float)(HH - 1));
    float wc = fminf(fmaxf(w, 0.0f), (float)(WW - 1));
    int h0 = (int)hc, w0 = (int)wc;
    int h1 = min(h0 + 1, HH - 1), w1i = min(w0 + 1, WW - 1);
    float lh = hc - (float)h0, lw = wc - (float)w0;
    float w00 = (1.0f - lh) * (1.0f - lw), w01 = (1.0f - lh) * lw;
    float w10 = lh * (1.0f - lw), w11 = lh * lw;
    if (!valid) { w00 = w01 = w10 = w11 = 0.0f; }
    s_c[si * 4 + 0] = { (h0 * WW + w0) * CC, w00 };
    s_c[si * 4 + 1] = { (h0 * WW + w1i) * CC, w01 };
    s_c[si * 4 + 2] = { (h1 * WW + w0) * CC, w10 };
    s_c[si * 4 + 3] = { (h1 * WW + w1i) * CC, w11 };
    s_vld[si] = valid ? 1.0f : 0.0f;
  }
  __syncthreads();
  if (tid < 49) {
    float cnt = 0.0f;
#pragma unroll
    for (int s = 0; s < 16; s++) cnt += s_vld[tid * 16 + s];
    float m = 1.0f;
    if (PASS2) {
      float mv = om[n * 147 + 98 + tid];
      m = 1.0f / (1.0f + expf(-mv));
    }
    s_scale[tid] = (cnt > 0.0f) ? m / cnt : 0.0f;
  }
  __syncthreads();

  // ---- phase 2: accumulate (wave per bin, lane = 4 channels) ----
  const int wv = tid >> 6;
  const int c4 = (tid & 63) * 4;
  for (int p = wv; p < 49; p += 8) {
    float a0 = 0.0f, a1 = 0.0f, a2 = 0.0f, a3 = 0.0f;
    const Corner* cp = &s_c[p * 64];
#pragma unroll 8
    for (int q = 0; q < 64; q++) {            // 16 samples x 4 corners, branch-free
      Corner cr = cp[q];
      int sidx = __builtin_amdgcn_readfirstlane(cr.idx);
      float sw = __uint_as_float(__builtin_amdgcn_readfirstlane(__float_as_uint(cr.w)));
      f16x4 v = *(const f16x4*)(fb + sidx + c4);
      a0 += sw * (float)v[0];
      a1 += sw * (float)v[1];
      a2 += sw * (float)v[2];
      a3 += sw * (float)v[3];
    }
    float sc = s_scale[p];
    a0 *= sc; a1 *= sc; a2 *= sc; a3 *= sc;
    if (PASS2) {
      s_outf[(c4 + 0) * 49 + p] = a0;
      s_outf[(c4 + 1) * 49 + p] = a1;
      s_outf[(c4 + 2) * 49 + p] = a2;
      s_outf[(c4 + 3) * 49 + p] = a3;
    } else {
      s_outh[(c4 + 0) * 49 + p] = (half_t)a0;
      s_outh[(c4 + 1) * 49 + p] = (half_t)a1;
      s_outh[(c4 + 2) * 49 + p] = (half_t)a2;
      s_outh[(c4 + 3) * 49 + p] = (half_t)a3;
    }
  }
  __syncthreads();

  // ---- phase 3: coalesced write-out ----
  if (PASS2) {
    float* ob = out + (size_t)n * KDIM;
    for (int l = tid * 4; l < KDIM; l += 2048)
      *(float4*)(ob + l) = *(const float4*)(s_outf + l);
  } else {
    half_t* ob = xout + (size_t)n * KDIM;        // layout k = c*49+p (w1-native)
    for (int l = tid * 8; l < KDIM; l += 4096)
      *(f16x8*)(ob + l) = *(const f16x8*)(s_outh + l);
  }
}

// ---- split-K fp16 MFMA GEMM, BLOCKED partial output ----
// P layout: [z][tile=by*8+bx][wave][reg][lane]  (reg = i*16+j*4+rr)
// -> every accumulator store is 64 lanes x 4B = 256B contiguous (no write
//    amplification, no L2 write-allocate reads).
template <int SK>
__global__ __launch_bounds__(256, 4) void gemm_sk(const half_t* __restrict__ A,
                                                  const half_t* __restrict__ B,
                                                  float* __restrict__ P,
                                                  int M, int N, int K) {
  __shared__ half_t As[64 * 72];
  __shared__ half_t Bs[128 * 72];
  const int m0 = blockIdx.x * 64;
  const int n0 = blockIdx.y * 128;
  const int Kc = K / SK;
  const int kbeg = blockIdx.z * Kc;
  const int tid = threadIdx.x;
  const int lane = tid & 63;
  const int wave = tid >> 6;
  const int wm = (wave & 1) * 32;
  const int wn = (wave >> 1) * 64;
  const int lrow = tid >> 3;
  const int lcol = (tid & 7) * 8;
  const int fr = lane & 15;
  const int fk0 = (lane >> 4) * 8;
  f32x4 acc[2][4] = {};
  const half_t* Ap = A + (size_t)(m0 + lrow) * K + kbeg + lcol;
  const half_t* Bp = B + (size_t)(n0 + lrow) * K + kbeg + lcol;
  uint4 ra[2], rb[4];
  ra[0] = *(const uint4*)(Ap);
  ra[1] = *(const uint4*)(Ap + (size_t)32 * K);
#pragma unroll
  for (int p = 0; p < 4; p++) rb[p] = *(const uint4*)(Bp + (size_t)(32 * p) * K);
  const int iters = Kc >> 6;
  for (int it = 0; it < iters; it++) {
    *(uint4*)&As[lrow * 72 + lcol] = ra[0];
    *(uint4*)&As[(lrow + 32) * 72 + lcol] = ra[1];
#pragma unroll
    for (int p = 0; p < 4; p++) *(uint4*)&Bs[(lrow + 32 * p) * 72 + lcol] = rb[p];
    __syncthreads();
    if (it + 1 < iters) {
      int ko = (it + 1) * 64;
      ra[0] = *(const uint4*)(Ap + ko);
      ra[1] = *(const uint4*)(Ap + (size_t)32 * K + ko);
#pragma unroll
      for (int p = 0; p < 4; p++) rb[p] = *(const uint4*)(Bp + (size_t)(32 * p) * K + ko);
    }
#pragma unroll
    for (int ks = 0; ks < 2; ks++) {
      const int fk = fk0 + ks * 32;
      f16x8 af[2], bf[4];
      af[0] = *(const f16x8*)&As[(wm + fr) * 72 + fk];
      af[1] = *(const f16x8*)&As[(wm + 16 + fr) * 72 + fk];
#pragma unroll
      for (int j = 0; j < 4; j++) bf[j] = *(const f16x8*)&Bs[(wn + j * 16 + fr) * 72 + fk];
#pragma unroll
      for (int i = 0; i < 2; i++)
#pragma unroll
        for (int j = 0; j < 4; j++)
          acc[i][j] = __builtin_amdgcn_mfma_f32_16x16x32_f16(af[i], bf[j], acc[i][j], 0, 0, 0);
    }
    __syncthreads();
  }
  // blocked store: 256B contiguous per (reg) store
  float* Pz = P + ((((size_t)blockIdx.z * 64 + blockIdx.y * 8 + blockIdx.x) * 4 + wave) * 32) * 64;
#pragma unroll
  for (int i = 0; i < 2; i++)
#pragma unroll
    for (int j = 0; j < 4; j++)
#pragma unroll
      for (int rr = 0; rr < 4; rr++)
        Pz[(i * 16 + j * 4 + rr) * 64 + lane] = acc[i][j][rr];
}

// ---- reduce SK blocked partials + bias (+relu), write fp16 or fp32 ----
// Decodes (row,col) from the blocked index; reads are perfectly coalesced.
template <bool OUT16, bool RELU, int SK>
__global__ __launch_bounds__(256) void reduce_blocked(const float* __restrict__ P,
                                                      const float* __restrict__ bias,
                                                      void* __restrict__ out,
                                                      int MN, int N) {
  int i4 = (blockIdx.x * 256 + threadIdx.x) * 4;
  if (i4 >= MN) return;
  float4 s = *(const float4*)(P + i4);
#pragma unroll
  for (int z = 1; z < SK; z++) {
    float4 t = *(const float4*)(P + (size_t)z * MN + i4);
    s.x += t.x; s.y += t.y; s.z += t.z; s.w += t.w;
  }
  // decode blocked index -> (row, col)
  const int lane0 = i4 & 63;
  const int q     = (i4 >> 6) & 31;
  const int wave  = (i4 >> 11) & 3;
  const int bx    = (i4 >> 13) & 7;
  const int by    = (i4 >> 16) & 7;
  const int i_ = q >> 4, j_ = (q >> 2) & 3, rr = q & 3;
  const int row = bx * 64 + (wave & 1) * 32 + i_ * 16 + (lane0 >> 4) * 4 + rr;
  const int col = by * 128 + (wave >> 1) * 64 + j_ * 16 + (lane0 & 15);
  float4 bv = *(const float4*)(bias + col);
  s.x += bv.x; s.y += bv.y; s.z += bv.z; s.w += bv.w;
  if (RELU) {
    s.x = fmaxf(s.x, 0.0f); s.y = fmaxf(s.y, 0.0f);
    s.z = fmaxf(s.z, 0.0f); s.w = fmaxf(s.w, 0.0f);
  }
  size_t o = (size_t)row * N + col;
  if (OUT16) {
    f16x4 ov;
    ov[0] = (half_t)s.x; ov[1] = (half_t)s.y; ov[2] = (half_t)s.z; ov[3] = (half_t)s.w;
    *(f16x4*)((half_t*)out + o) = ov;
  } else {
    *(float4*)((float*)out + o) = s;
  }
}

// ---------------- fp32 GEMM3: om(N,147) = h2(N,1024) @ w3(147,1024)^T + b3 ----------------
__global__ __launch_bounds__(192) void gemm_small(const float* __restrict__ h2,
                                                  const float* __restrict__ w3,
                                                  const float* __restrict__ b3,
                                                  float* __restrict__ om) {
  __shared__ float hs[FC];
  int n = blockIdx.x;
  for (int k = threadIdx.x; k < FC; k += 192) hs[k] = h2[(size_t)n * FC + k];
  __syncthreads();
  int j = threadIdx.x;
  if (j < 147) {
    float acc = b3[j];
    const float* wr = w3 + (size_t)j * FC;
    for (int k = 0; k < FC; k += 4) {
      float4 wv = *(const float4*)(wr + k);
      acc += hs[k] * wv.x + hs[k + 1] * wv.y + hs[k + 2] * wv.z + hs[k + 3] * wv.w;
    }
    om[n * 147 + j] = acc;
  }
}

extern "C" void kernel_launch(void* const* d_in, const int* in_sizes, int n_in,
                              void* d_out, int out_size, void* d_ws, size_t ws_size,
                              hipStream_t stream) {
  const float* feat = (const float*)d_in[0];
  const float* rois = (const float*)d_in[1];
  const float* w1 = (const float*)d_in[2];
  const float* b1 = (const float*)d_in[3];
  const float* w2 = (const float*)d_in[4];
  const float* b2 = (const float*)d_in[5];
  const float* w3 = (const float*)d_in[6];
  const float* b3 = (const float*)d_in[7];
  float* out = (float*)d_out;
  char* ws = (char*)d_ws;

  // workspace carve (~83.7 MB total)
  half_t* featT = (half_t*)ws;                        // 10,240,000 B
  half_t* xh    = (half_t*)(ws + 10240000);           // 12,845,056 B  (k = c*49+p)
  half_t* w1h   = (half_t*)(ws + 23085056);           // 25,690,112 B  (raw layout)
  half_t* w2h   = (half_t*)(ws + 48775168);           //  2,097,152 B
  half_t* h1    = (half_t*)(ws + 50872320);           //  1,048,576 B
  float*  h2    = (float*)(ws + 51920896);            //  2,097,152 B
  float*  omb   = (float*)(ws + 54018048);            //    301,056 B
  float*  part  = (float*)(ws + 54319104);            // 29,360,128 B

  const int MN = NROI * FC;  // 524288

  transpose_feat<<<dim3(313, 8, 2), dim3(32, 8), 0, stream>>>(feat, featT);
  convert_f32_f16<<<dim3(12544), dim3(256), 0, stream>>>(w1, w1h, FC * KDIM);
  convert_f32_f16<<<dim3(1024), dim3(256), 0, stream>>>(w2, w2h, FC * FC);
  pool_kernel<false><<<dim3(NROI), dim3(512), 0, stream>>>(featT, rois, nullptr, xh, nullptr);

  // GEMM1: (512x12544) @ (1024x12544)^T -> SK=14, 896 blocks
  gemm_sk<14><<<dim3(8, 8, 14), dim3(256), 0, stream>>>(xh, w1h, part, NROI, FC, KDIM);
  reduce_blocked<true, true, 14><<<dim3(MN / 1024), dim3(256), 0, stream>>>(part, b1, (void*)h1, MN, FC);

  // GEMM2: (512x1024) @ (1024x1024)^T -> SK=8, 512 blocks
  gemm_sk<8><<<dim3(8, 8, 8), dim3(256), 0, stream>>>(h1, w2h, part, NROI, FC, FC);
  reduce_blocked<false, true, 8><<<dim3(MN / 1024), dim3(256), 0, stream>>>(part, b2, (void*)h2, MN, FC);

  gemm_small<<<dim3(NROI), dim3(192), 0, stream>>>(h2, w3, b3, omb);
  pool_kernel<true><<<dim3(NROI), dim3(512), 0, stream>>>(featT, rois, omb, nullptr, out);
}

// Round 6
// 360.164 us; speedup vs baseline: 1.1245x; 1.1245x over previous
//
#include <hip/hip_runtime.h>

// Problem constants (fixed by setup_inputs)
#define BB 2
#define CC 256
#define HH 100
#define WW 100
#define NROI 512
#define KDIM 12544   // 49*256
#define FC 1024

typedef _Float16 half_t;
typedef _Float16 f16x2 __attribute__((ext_vector_type(2)));
typedef _Float16 f16x8 __attribute__((ext_vector_type(8)));
typedef _Float16 f16x4 __attribute__((ext_vector_type(4)));
typedef float f32x4 __attribute__((ext_vector_type(4)));

// ---------------- feat (B,C,H,W) fp32 -> featT (B,H*W,C) fp16 ----------------
__global__ __launch_bounds__(256) void transpose_feat(const float* __restrict__ feat,
                                                      half_t* __restrict__ featT) {
  __shared__ float tile[32][33];
  int b = blockIdx.z;
  int hw0 = blockIdx.x * 32;
  int c0 = blockIdx.y * 32;
  int tx = threadIdx.x, ty = threadIdx.y;
  const float* fb = feat + (size_t)b * CC * (HH * WW);
#pragma unroll
  for (int i = 0; i < 4; i++) {
    int c = c0 + ty + i * 8;
    int hw = hw0 + tx;
    tile[ty + i * 8][tx] = (hw < HH * WW) ? fb[(size_t)c * (HH * WW) + hw] : 0.0f;
  }
  __syncthreads();
  half_t* ob = featT + (size_t)b * (HH * WW) * CC;
#pragma unroll
  for (int i = 0; i < 4; i++) {
    int hw = hw0 + ty + i * 8;
    int c = c0 + tx;
    if (hw < HH * WW) ob[(size_t)hw * CC + c] = (half_t)tile[tx][ty + i * 8];
  }
}

// ---------------- fp32 -> fp16 convert (w1, w2) ----------------
__global__ __launch_bounds__(256) void convert_f32_f16(const float* __restrict__ in,
                                                       half_t* __restrict__ out, int n) {
  int i4 = (blockIdx.x * 256 + threadIdx.x) * 4;
  if (i4 < n) {
    float4 v = *(const float4*)(in + i4);
    f16x4 o;
    o[0] = (half_t)v.x; o[1] = (half_t)v.y; o[2] = (half_t)v.z; o[3] = (half_t)v.w;
    *(f16x4*)(out + i4) = o;
  }
}

// ---------------- deformable PSROI pooling, one block (512 thr) per ROI ----------------
template <bool PASS2>
__global__ __launch_bounds__(512) void pool_kernel(const half_t* __restrict__ featT,
                                                   const float* __restrict__ rois,
                                                   const float* __restrict__ om,
                                                   half_t* __restrict__ xout,
                                                   float* __restrict__ out) {
  struct Corner { int idx; float w; };
  __shared__ Corner s_c[784 * 4];                     // 25088 B
  __shared__ float s_vld[784];                        //  3136 B
  __shared__ float s_scale[49];
  __shared__ float  s_outf[PASS2 ? KDIM : 1];         // 50176 B (PASS2)
  __shared__ half_t s_outh[PASS2 ? 1 : KDIM];         // 25088 B (PASS1)

  const int n = blockIdx.x;
  const int tid = threadIdx.x;
  const float* r = rois + n * 5;
  const int b = (int)r[0];
  const float rsw = rintf(r[1]) * 0.0625f - 0.5f;     // rintf = round-half-even = jnp.round
  const float rsh = rintf(r[2]) * 0.0625f - 0.5f;
  const float rew = (rintf(r[3]) + 1.0f) * 0.0625f - 0.5f;
  const float reh = (rintf(r[4]) + 1.0f) * 0.0625f - 0.5f;
  const float roi_w = fmaxf(rew - rsw, 0.1f);
  const float roi_h = fmaxf(reh - rsh, 0.1f);
  const float bin_h = roi_h / 7.0f, bin_w = roi_w / 7.0f;
  const float sub_h = bin_h * 0.25f, sub_w = bin_w * 0.25f;
  const half_t* fb = featT + (size_t)b * (HH * WW) * CC;

  // ---- phase 1: sample metadata ----
  for (int si = tid; si < 784; si += 512) {
    int p = si >> 4, s = si & 15;
    int ph = p / 7, pw = p - ph * 7;
    float tx = 0.0f, ty = 0.0f;
    if (PASS2) {
      tx = om[n * 147 + p] * 0.1f;          // part_h == ph (verified)
      ty = om[n * 147 + 49 + p] * 0.1f;
    }
    float h = (float)ph * bin_h + rsh + ty * roi_h + (float)(s >> 2) * sub_h;
    float w = (float)pw * bin_w + rsw + tx * roi_w + (float)(s & 3) * sub_w;
    bool valid = (w >= -0.5f) && (w <= (float)WW - 0.5f) &&
                 (h >= -0.5f) && (h <= (float)HH - 0.5f);
    float hc = fminf(fmaxf(h, 0.0f), (float)(HH - 1));
    float wc = fminf(fmaxf(w, 0.0f), (float)(WW - 1));
    int h0 = (int)hc, w0 = (int)wc;
    int h1 = min(h0 + 1, HH - 1), w1i = min(w0 + 1, WW - 1);
    float lh = hc - (float)h0, lw = wc - (float)w0;
    float w00 = (1.0f - lh) * (1.0f - lw), w01 = (1.0f - lh) * lw;
    float w10 = lh * (1.0f - lw), w11 = lh * lw;
    if (!valid) { w00 = w01 = w10 = w11 = 0.0f; }
    s_c[si * 4 + 0] = { (h0 * WW + w0) * CC, w00 };
    s_c[si * 4 + 1] = { (h0 * WW + w1i) * CC, w01 };
    s_c[si * 4 + 2] = { (h1 * WW + w0) * CC, w10 };
    s_c[si * 4 + 3] = { (h1 * WW + w1i) * CC, w11 };
    s_vld[si] = valid ? 1.0f : 0.0f;
  }
  __syncthreads();
  if (tid < 49) {
    float cnt = 0.0f;
#pragma unroll
    for (int s = 0; s < 16; s++) cnt += s_vld[tid * 16 + s];
    float m = 1.0f;
    if (PASS2) {
      float mv = om[n * 147 + 98 + tid];
      m = 1.0f / (1.0f + expf(-mv));
    }
    s_scale[tid] = (cnt > 0.0f) ? m / cnt : 0.0f;
  }
  __syncthreads();

  // ---- phase 2: accumulate (wave per bin, lane = 4 channels) ----
  const int wv = tid >> 6;
  const int c4 = (tid & 63) * 4;
  for (int p = wv; p < 49; p += 8) {
    float a0 = 0.0f, a1 = 0.0f, a2 = 0.0f, a3 = 0.0f;
    const Corner* cp = &s_c[p * 64];
#pragma unroll 8
    for (int q = 0; q < 64; q++) {            // 16 samples x 4 corners, branch-free
      Corner cr = cp[q];
      int sidx = __builtin_amdgcn_readfirstlane(cr.idx);
      float sw = __uint_as_float(__builtin_amdgcn_readfirstlane(__float_as_uint(cr.w)));
      f16x4 v = *(const f16x4*)(fb + sidx + c4);
      a0 += sw * (float)v[0];
      a1 += sw * (float)v[1];
      a2 += sw * (float)v[2];
      a3 += sw * (float)v[3];
    }
    float sc = s_scale[p];
    a0 *= sc; a1 *= sc; a2 *= sc; a3 *= sc;
    if (PASS2) {
      s_outf[(c4 + 0) * 49 + p] = a0;
      s_outf[(c4 + 1) * 49 + p] = a1;
      s_outf[(c4 + 2) * 49 + p] = a2;
      s_outf[(c4 + 3) * 49 + p] = a3;
    } else {
      s_outh[(c4 + 0) * 49 + p] = (half_t)a0;
      s_outh[(c4 + 1) * 49 + p] = (half_t)a1;
      s_outh[(c4 + 2) * 49 + p] = (half_t)a2;
      s_outh[(c4 + 3) * 49 + p] = (half_t)a3;
    }
  }
  __syncthreads();

  // ---- phase 3: coalesced write-out ----
  if (PASS2) {
    float* ob = out + (size_t)n * KDIM;
    for (int l = tid * 4; l < KDIM; l += 2048)
      *(float4*)(ob + l) = *(const float4*)(s_outf + l);
  } else {
    half_t* ob = xout + (size_t)n * KDIM;        // layout k = c*49+p (w1-native)
    for (int l = tid * 8; l < KDIM; l += 4096)
      *(f16x8*)(ob + l) = *(const f16x8*)(s_outh + l);
  }
}

// ---- split-K fp16 MFMA GEMM: 256(M)x128(N) tile, BK=64, 512 thr / 8 waves ----
// Wave = 64x64 via 4x4 of 16x16x32 MFMA. XOR-swizzled LDS (chunk c -> c^(row&7)):
// no padding (48KB total), conflict-free ds_write/ds_read, linear coalesced
// global reads. Register prefetch of next tile. Blocked P store (256B/wave-store).
// P layout: [z][tile=by*2+bx][wave][q=(i*4+j)*4+rr][lane]
template <int SK>
__global__ __launch_bounds__(512) void gemm_sk(const half_t* __restrict__ A,
                                               const half_t* __restrict__ B,
                                               float* __restrict__ P,
                                               int M, int N, int K) {
  __shared__ half_t As[256 * 64];   // 32 KB
  __shared__ half_t Bs[128 * 64];   // 16 KB
  const int m0 = blockIdx.x * 256;
  const int n0 = blockIdx.y * 128;
  const int Kc = K / SK;
  const int kbeg = blockIdx.z * Kc;
  const int tid = threadIdx.x;
  const int lane = tid & 63;
  const int wave = tid >> 6;
  const int wm = (wave & 3) * 64;
  const int wn = (wave >> 2) * 64;
  const int r = tid >> 3;                 // 0..63 staging row
  const int cg = tid & 7;                 // linear global chunk (16B)
  const int csw = (cg ^ (r & 7)) * 8;     // swizzled LDS chunk offset (halfs)
  const int fr = lane & 15;
  const int kc0 = lane >> 4;              // 0..3
  f32x4 acc[4][4] = {};
  const half_t* Ap = A + (size_t)(m0 + r) * K + kbeg + cg * 8;
  const half_t* Bp = B + (size_t)(n0 + r) * K + kbeg + cg * 8;
  uint4 ra[4], rb[2];
#pragma unroll
  for (int s = 0; s < 4; s++) ra[s] = *(const uint4*)(Ap + (size_t)(64 * s) * K);
#pragma unroll
  for (int s = 0; s < 2; s++) rb[s] = *(const uint4*)(Bp + (size_t)(64 * s) * K);
  const int iters = Kc >> 6;
  for (int it = 0; it < iters; it++) {
#pragma unroll
    for (int s = 0; s < 4; s++) *(uint4*)&As[(r + 64 * s) * 64 + csw] = ra[s];
#pragma unroll
    for (int s = 0; s < 2; s++) *(uint4*)&Bs[(r + 64 * s) * 64 + csw] = rb[s];
    __syncthreads();
    if (it + 1 < iters) {     // prefetch next K-tile during MFMA phase
      int ko = (it + 1) * 64;
#pragma unroll
      for (int s = 0; s < 4; s++) ra[s] = *(const uint4*)(Ap + (size_t)(64 * s) * K + ko);
#pragma unroll
      for (int s = 0; s < 2; s++) rb[s] = *(const uint4*)(Bp + (size_t)(64 * s) * K + ko);
    }
#pragma unroll
    for (int ks = 0; ks < 2; ks++) {
      const int swz = ((kc0 + ks * 4) ^ (fr & 7)) * 8;
      f16x8 af[4], bf[4];
#pragma unroll
      for (int i = 0; i < 4; i++) af[i] = *(const f16x8*)&As[(wm + i * 16 + fr) * 64 + swz];
#pragma unroll
      for (int j = 0; j < 4; j++) bf[j] = *(const f16x8*)&Bs[(wn + j * 16 + fr) * 64 + swz];
#pragma unroll
      for (int i = 0; i < 4; i++)
#pragma unroll
        for (int j = 0; j < 4; j++)
          acc[i][j] = __builtin_amdgcn_mfma_f32_16x16x32_f16(af[i], bf[j], acc[i][j], 0, 0, 0);
    }
    __syncthreads();
  }
  // blocked store: 256B contiguous per (q) store
  float* Pz = P + (((size_t)blockIdx.z * 16 + blockIdx.y * 2 + blockIdx.x) * 8 + wave) * 4096;
#pragma unroll
  for (int i = 0; i < 4; i++)
#pragma unroll
    for (int j = 0; j < 4; j++)
#pragma unroll
      for (int rr = 0; rr < 4; rr++)
        Pz[((i * 4 + j) * 4 + rr) * 64 + lane] = acc[i][j][rr];
}

// ---- reduce SK blocked partials + bias (+relu), write fp16 or fp32 ----
template <bool OUT16, bool RELU, int SK>
__global__ __launch_bounds__(256) void reduce_blocked(const float* __restrict__ P,
                                                      const float* __restrict__ bias,
                                                      void* __restrict__ out,
                                                      int MN, int N) {
  int i4 = (blockIdx.x * 256 + threadIdx.x) * 4;
  if (i4 >= MN) return;
  float4 s = *(const float4*)(P + i4);
#pragma unroll
  for (int z = 1; z < SK; z++) {
    float4 t = *(const float4*)(P + (size_t)z * MN + i4);
    s.x += t.x; s.y += t.y; s.z += t.z; s.w += t.w;
  }
  // decode blocked index -> (row, col)
  const int lane0 = i4 & 63;
  const int q     = (i4 >> 6) & 63;
  const int wave  = (i4 >> 12) & 7;
  const int tile  = (i4 >> 15) & 15;
  const int rr = q & 3, j_ = (q >> 2) & 3, i_ = q >> 4;
  const int bx = tile & 1, by = tile >> 1;
  const int row = bx * 256 + (wave & 3) * 64 + i_ * 16 + (lane0 >> 4) * 4 + rr;
  const int col = by * 128 + (wave >> 2) * 64 + j_ * 16 + (lane0 & 15);
  float4 bv = *(const float4*)(bias + col);
  s.x += bv.x; s.y += bv.y; s.z += bv.z; s.w += bv.w;
  if (RELU) {
    s.x = fmaxf(s.x, 0.0f); s.y = fmaxf(s.y, 0.0f);
    s.z = fmaxf(s.z, 0.0f); s.w = fmaxf(s.w, 0.0f);
  }
  size_t o = (size_t)row * N + col;
  if (OUT16) {
    f16x4 ov;
    ov[0] = (half_t)s.x; ov[1] = (half_t)s.y; ov[2] = (half_t)s.z; ov[3] = (half_t)s.w;
    *(f16x4*)((half_t*)out + o) = ov;
  } else {
    *(float4*)((float*)out + o) = s;
  }
}

// ---------------- fp32 GEMM3: om(N,147) = h2(N,1024) @ w3(147,1024)^T + b3 ----------------
__global__ __launch_bounds__(192) void gemm_small(const float* __restrict__ h2,
                                                  const float* __restrict__ w3,
                                                  const float* __restrict__ b3,
                                                  float* __restrict__ om) {
  __shared__ float hs[FC];
  int n = blockIdx.x;
  for (int k = threadIdx.x; k < FC; k += 192) hs[k] = h2[(size_t)n * FC + k];
  __syncthreads();
  int j = threadIdx.x;
  if (j < 147) {
    float acc = b3[j];
    const float* wr = w3 + (size_t)j * FC;
    for (int k = 0; k < FC; k += 4) {
      float4 wv = *(const float4*)(wr + k);
      acc += hs[k] * wv.x + hs[k + 1] * wv.y + hs[k + 2] * wv.z + hs[k + 3] * wv.w;
    }
    om[n * 147 + j] = acc;
  }
}

extern "C" void kernel_launch(void* const* d_in, const int* in_sizes, int n_in,
                              void* d_out, int out_size, void* d_ws, size_t ws_size,
                              hipStream_t stream) {
  const float* feat = (const float*)d_in[0];
  const float* rois = (const float*)d_in[1];
  const float* w1 = (const float*)d_in[2];
  const float* b1 = (const float*)d_in[3];
  const float* w2 = (const float*)d_in[4];
  const float* b2 = (const float*)d_in[5];
  const float* w3 = (const float*)d_in[6];
  const float* b3 = (const float*)d_in[7];
  float* out = (float*)d_out;
  char* ws = (char*)d_ws;

  // workspace carve (~83.7 MB total)
  half_t* featT = (half_t*)ws;                        // 10,240,000 B
  half_t* xh    = (half_t*)(ws + 10240000);           // 12,845,056 B  (k = c*49+p)
  half_t* w1h   = (half_t*)(ws + 23085056);           // 25,690,112 B  (raw layout)
  half_t* w2h   = (half_t*)(ws + 48775168);           //  2,097,152 B
  half_t* h1    = (half_t*)(ws + 50872320);           //  1,048,576 B
  float*  h2    = (float*)(ws + 51920896);            //  2,097,152 B
  float*  omb   = (float*)(ws + 54018048);            //    301,056 B
  float*  part  = (float*)(ws + 54319104);            // 29,360,128 B

  const int MN = NROI * FC;  // 524288

  transpose_feat<<<dim3(313, 8, 2), dim3(32, 8), 0, stream>>>(feat, featT);
  convert_f32_f16<<<dim3(12544), dim3(256), 0, stream>>>(w1, w1h, FC * KDIM);
  convert_f32_f16<<<dim3(1024), dim3(256), 0, stream>>>(w2, w2h, FC * FC);
  pool_kernel<false><<<dim3(NROI), dim3(512), 0, stream>>>(featT, rois, nullptr, xh, nullptr);

  // GEMM1: (512x12544) @ (1024x12544)^T -> 256x128 tiles, SK=14, 224 blocks
  gemm_sk<14><<<dim3(2, 8, 14), dim3(512), 0, stream>>>(xh, w1h, part, NROI, FC, KDIM);
  reduce_blocked<true, true, 14><<<dim3(MN / 1024), dim3(256), 0, stream>>>(part, b1, (void*)h1, MN, FC);

  // GEMM2: (512x1024) @ (1024x1024)^T -> SK=8, 128 blocks
  gemm_sk<8><<<dim3(2, 8, 8), dim3(512), 0, stream>>>(h1, w2h, part, NROI, FC, FC);
  reduce_blocked<false, true, 8><<<dim3(MN / 1024), dim3(256), 0, stream>>>(part, b2, (void*)h2, MN, FC);

  gemm_small<<<dim3(NROI), dim3(192), 0, stream>>>(h2, w3, b3, omb);
  pool_kernel<true><<<dim3(NROI), dim3(512), 0, stream>>>(featT, rois, omb, nullptr, out);
}

// Round 7
// 306.631 us; speedup vs baseline: 1.3208x; 1.1746x over previous
//
#include <hip/hip_runtime.h>

// Problem constants (fixed by setup_inputs)
#define BB 2
#define CC 256
#define HH 100
#define WW 100
#define NROI 512
#define KDIM 12544   // 49*256
#define FC 1024

typedef _Float16 half_t;
typedef _Float16 f16x2 __attribute__((ext_vector_type(2)));
typedef _Float16 f16x8 __attribute__((ext_vector_type(8)));
typedef _Float16 f16x4 __attribute__((ext_vector_type(4)));
typedef float f32x4 __attribute__((ext_vector_type(4)));

// ---------------- feat (B,C,H,W) fp32 -> featT (B,H*W,C) fp16 ----------------
__global__ __launch_bounds__(256) void transpose_feat(const float* __restrict__ feat,
                                                      half_t* __restrict__ featT) {
  __shared__ float tile[32][33];
  int b = blockIdx.z;
  int hw0 = blockIdx.x * 32;
  int c0 = blockIdx.y * 32;
  int tx = threadIdx.x, ty = threadIdx.y;
  const float* fb = feat + (size_t)b * CC * (HH * WW);
#pragma unroll
  for (int i = 0; i < 4; i++) {
    int c = c0 + ty + i * 8;
    int hw = hw0 + tx;
    tile[ty + i * 8][tx] = (hw < HH * WW) ? fb[(size_t)c * (HH * WW) + hw] : 0.0f;
  }
  __syncthreads();
  half_t* ob = featT + (size_t)b * (HH * WW) * CC;
#pragma unroll
  for (int i = 0; i < 4; i++) {
    int hw = hw0 + ty + i * 8;
    int c = c0 + tx;
    if (hw < HH * WW) ob[(size_t)hw * CC + c] = (half_t)tile[tx][ty + i * 8];
  }
}

// ---------------- fp32 -> fp16 convert (w1, w2) ----------------
__global__ __launch_bounds__(256) void convert_f32_f16(const float* __restrict__ in,
                                                       half_t* __restrict__ out, int n) {
  int i4 = (blockIdx.x * 256 + threadIdx.x) * 4;
  if (i4 < n) {
    float4 v = *(const float4*)(in + i4);
    f16x4 o;
    o[0] = (half_t)v.x; o[1] = (half_t)v.y; o[2] = (half_t)v.z; o[3] = (half_t)v.w;
    *(f16x4*)(out + i4) = o;
  }
}

// ---------------- deformable PSROI pooling, one block (512 thr) per ROI ----------------
// Separable dedup: validity (vh_i & vw_j) and bilinear weights factor per axis, so
// sum over 16 samples x 4 corners == sum over <=5x5 unique pixels with weight
// wh[r]*ww[c]; cnt == (sum vh)(sum vw). Exact in reals; ~2.6x fewer gathers.
struct PixW { int idx; float w; };

template <bool PASS2>
__global__ __launch_bounds__(512) void pool_kernel(const half_t* __restrict__ featT,
                                                   const float* __restrict__ rois,
                                                   const float* __restrict__ om,
                                                   half_t* __restrict__ xout,
                                                   float* __restrict__ out) {
  __shared__ PixW s_pix[49 * 28];                     // 10976 B (<=25 pixels + pad)
  __shared__ int s_cnt[49];
  __shared__ float s_scale[49];
  __shared__ float  s_outf[PASS2 ? KDIM : 1];         // 50176 B (PASS2)
  __shared__ half_t s_outh[PASS2 ? 1 : KDIM];         // 25088 B (PASS1)

  const int n = blockIdx.x;
  const int tid = threadIdx.x;
  const float* r = rois + n * 5;
  const int b = (int)r[0];
  const float rsw = rintf(r[1]) * 0.0625f - 0.5f;     // rintf = round-half-even = jnp.round
  const float rsh = rintf(r[2]) * 0.0625f - 0.5f;
  const float rew = (rintf(r[3]) + 1.0f) * 0.0625f - 0.5f;
  const float reh = (rintf(r[4]) + 1.0f) * 0.0625f - 0.5f;
  const float roi_w = fmaxf(rew - rsw, 0.1f);
  const float roi_h = fmaxf(reh - rsh, 0.1f);
  const float bin_h = roi_h / 7.0f, bin_w = roi_w / 7.0f;
  const float sub_h = bin_h * 0.25f, sub_w = bin_w * 0.25f;
  const half_t* fb = featT + (size_t)b * (HH * WW) * CC;

  // ---- phase 1: per-bin separable weights -> dedup'd pixel list ----
  if (tid < 49) {
    const int p = tid, ph = p / 7, pw = p - ph * 7;
    float tx = 0.0f, ty = 0.0f, mask = 1.0f;
    if (PASS2) {
      tx = om[n * 147 + p] * 0.1f;          // part_h == ph (verified)
      ty = om[n * 147 + 49 + p] * 0.1f;
      mask = 1.0f / (1.0f + expf(-om[n * 147 + 98 + p]));
    }
    const float hst = (float)ph * bin_h + rsh + ty * roi_h;
    const float wst = (float)pw * bin_w + rsw + tx * roi_w;
    // row axis (sub_h*3 <= 2.7 -> span <= 3 -> indices fit [0,4]; [6] defensive)
    float wh[6] = {0, 0, 0, 0, 0, 0};
    float hc0 = fminf(fmaxf(hst, 0.0f), 99.0f);
    const int r0 = (int)hc0;
    int rtop = r0;
    float vsh = 0.0f;
#pragma unroll
    for (int i = 0; i < 4; i++) {
      float h = hst + (float)i * sub_h;
      bool v = (h >= -0.5f) && (h <= (float)HH - 0.5f);
      float hc = fminf(fmaxf(h, 0.0f), 99.0f);
      int h0 = (int)hc;
      float lh = hc - (float)h0;
      int h1 = min(h0 + 1, HH - 1);
      if (v) { wh[h0 - r0] += 1.0f - lh; wh[h1 - r0] += lh; vsh += 1.0f; }
      rtop = h1;
    }
    // col axis
    float wwc[6] = {0, 0, 0, 0, 0, 0};
    float wc0 = fminf(fmaxf(wst, 0.0f), 99.0f);
    const int c0 = (int)wc0;
    int ctop = c0;
    float vsw = 0.0f;
#pragma unroll
    for (int j = 0; j < 4; j++) {
      float w = wst + (float)j * sub_w;
      bool v = (w >= -0.5f) && (w <= (float)WW - 0.5f);
      float wc = fminf(fmaxf(w, 0.0f), 99.0f);
      int w0 = (int)wc;
      float lw = wc - (float)w0;
      int w1 = min(w0 + 1, WW - 1);
      if (v) { wwc[w0 - c0] += 1.0f - lw; wwc[w1 - c0] += lw; vsw += 1.0f; }
      ctop = w1;
    }
    const int nr = rtop - r0 + 1, nc = ctop - c0 + 1;   // <= 5 each
    float cntf = vsh * vsw;
    s_scale[p] = (cntf > 0.0f) ? mask / cntf : 0.0f;
    PixW* dst = &s_pix[p * 28];
    int m = 0;
    for (int ri = 0; ri < nr; ri++) {
      int rowoff = (r0 + ri) * WW + c0;
      for (int ci = 0; ci < nc; ci++) {
        dst[m].idx = (rowoff + ci) * CC;
        dst[m].w = wh[ri] * wwc[ci];
        m++;
      }
    }
    while (m & 3) { dst[m].idx = 0; dst[m].w = 0.0f; m++; }   // pad to mult of 4
    s_cnt[p] = m;
  }
  __syncthreads();

  // ---- phase 2: accumulate (wave per bin, lane = 4 channels, 4 loads in flight) ----
  const int wv = tid >> 6;
  const int c4 = (tid & 63) * 4;
  for (int p = wv; p < 49; p += 8) {
    const int cnt = __builtin_amdgcn_readfirstlane(s_cnt[p]);
    const PixW* cp = &s_pix[p * 28];
    float a0 = 0.0f, a1 = 0.0f, a2 = 0.0f, a3 = 0.0f;
    for (int q = 0; q < cnt; q += 4) {
#pragma unroll
      for (int u = 0; u < 4; u++) {
        PixW e = cp[q + u];
        int si = __builtin_amdgcn_readfirstlane(e.idx);
        float sw = __uint_as_float(__builtin_amdgcn_readfirstlane(__float_as_uint(e.w)));
        f16x4 v = *(const f16x4*)(fb + si + c4);
        a0 += sw * (float)v[0];
        a1 += sw * (float)v[1];
        a2 += sw * (float)v[2];
        a3 += sw * (float)v[3];
      }
    }
    float sc = s_scale[p];
    a0 *= sc; a1 *= sc; a2 *= sc; a3 *= sc;
    if (PASS2) {
      s_outf[(c4 + 0) * 49 + p] = a0;
      s_outf[(c4 + 1) * 49 + p] = a1;
      s_outf[(c4 + 2) * 49 + p] = a2;
      s_outf[(c4 + 3) * 49 + p] = a3;
    } else {
      s_outh[(c4 + 0) * 49 + p] = (half_t)a0;
      s_outh[(c4 + 1) * 49 + p] = (half_t)a1;
      s_outh[(c4 + 2) * 49 + p] = (half_t)a2;
      s_outh[(c4 + 3) * 49 + p] = (half_t)a3;
    }
  }
  __syncthreads();

  // ---- phase 3: coalesced write-out ----
  if (PASS2) {
    float* ob = out + (size_t)n * KDIM;
    for (int l = tid * 4; l < KDIM; l += 2048)
      *(float4*)(ob + l) = *(const float4*)(s_outf + l);
  } else {
    half_t* ob = xout + (size_t)n * KDIM;        // layout k = c*49+p (w1-native)
    for (int l = tid * 8; l < KDIM; l += 4096)
      *(f16x8*)(ob + l) = *(const f16x8*)(s_outh + l);
  }
}

// ---- split-K fp16 MFMA GEMM: 128(M)x128(N) tile, BK=64, 256 thr / 4 waves ----
// 448 blocks for GEMM1 -> ~2 blocks/CU co-residency (hides barrier drains).
// Wave = 64x64 via 4x4 of 16x16x32 MFMA. XOR-swizzled LDS, conflict-free, 32 KB.
// Register prefetch of next K-tile. Blocked P store (256B contiguous per store).
// P layout: [z][tile=by*4+bx][wave][q=(i*4+j)*4+rr][lane]
template <int SK>
__global__ __launch_bounds__(256, 2) void gemm_sk(const half_t* __restrict__ A,
                                                  const half_t* __restrict__ B,
                                                  float* __restrict__ P,
                                                  int M, int N, int K) {
  __shared__ half_t As[128 * 64];   // 16 KB
  __shared__ half_t Bs[128 * 64];   // 16 KB
  const int m0 = blockIdx.x * 128;
  const int n0 = blockIdx.y * 128;
  const int Kc = K / SK;
  const int kbeg = blockIdx.z * Kc;
  const int tid = threadIdx.x;
  const int lane = tid & 63;
  const int wave = tid >> 6;
  const int wm = (wave & 1) * 64;
  const int wn = (wave >> 1) * 64;
  const int r = tid >> 3;                 // 0..31 staging row
  const int cg = tid & 7;                 // linear global chunk (16B)
  const int csw = (cg ^ (r & 7)) * 8;     // swizzled LDS chunk offset (halfs)
  const int fr = lane & 15;
  const int kc0 = lane >> 4;              // 0..3
  f32x4 acc[4][4] = {};
  const half_t* Ap = A + (size_t)(m0 + r) * K + kbeg + cg * 8;
  const half_t* Bp = B + (size_t)(n0 + r) * K + kbeg + cg * 8;
  uint4 ra[4], rb[4];
#pragma unroll
  for (int s = 0; s < 4; s++) ra[s] = *(const uint4*)(Ap + (size_t)(32 * s) * K);
#pragma unroll
  for (int s = 0; s < 4; s++) rb[s] = *(const uint4*)(Bp + (size_t)(32 * s) * K);
  const int iters = Kc >> 6;
  for (int it = 0; it < iters; it++) {
#pragma unroll
    for (int s = 0; s < 4; s++) *(uint4*)&As[(r + 32 * s) * 64 + csw] = ra[s];
#pragma unroll
    for (int s = 0; s < 4; s++) *(uint4*)&Bs[(r + 32 * s) * 64 + csw] = rb[s];
    __syncthreads();
    if (it + 1 < iters) {     // prefetch next K-tile during MFMA phase
      int ko = (it + 1) * 64;
#pragma unroll
      for (int s = 0; s < 4; s++) ra[s] = *(const uint4*)(Ap + (size_t)(32 * s) * K + ko);
#pragma unroll
      for (int s = 0; s < 4; s++) rb[s] = *(const uint4*)(Bp + (size_t)(32 * s) * K + ko);
    }
#pragma unroll
    for (int ks = 0; ks < 2; ks++) {
      const int swz = ((kc0 + ks * 4) ^ (fr & 7)) * 8;
      f16x8 af[4], bf[4];
#pragma unroll
      for (int i = 0; i < 4; i++) af[i] = *(const f16x8*)&As[(wm + i * 16 + fr) * 64 + swz];
#pragma unroll
      for (int j = 0; j < 4; j++) bf[j] = *(const f16x8*)&Bs[(wn + j * 16 + fr) * 64 + swz];
#pragma unroll
      for (int i = 0; i < 4; i++)
#pragma unroll
        for (int j = 0; j < 4; j++)
          acc[i][j] = __builtin_amdgcn_mfma_f32_16x16x32_f16(af[i], bf[j], acc[i][j], 0, 0, 0);
    }
    __syncthreads();
  }
  // blocked store: 256B contiguous per (q) store
  float* Pz = P + (((size_t)blockIdx.z * 32 + blockIdx.y * 4 + blockIdx.x) * 4 + wave) * 4096;
#pragma unroll
  for (int i = 0; i < 4; i++)
#pragma unroll
    for (int j = 0; j < 4; j++)
#pragma unroll
      for (int rr = 0; rr < 4; rr++)
        Pz[((i * 4 + j) * 4 + rr) * 64 + lane] = acc[i][j][rr];
}

// ---- reduce SK blocked partials + bias (+relu), write fp16 or fp32 ----
template <bool OUT16, bool RELU, int SK>
__global__ __launch_bounds__(256) void reduce_blocked(const float* __restrict__ P,
                                                      const float* __restrict__ bias,
                                                      void* __restrict__ out,
                                                      int MN, int N) {
  int i4 = (blockIdx.x * 256 + threadIdx.x) * 4;
  if (i4 >= MN) return;
  float4 s = *(const float4*)(P + i4);
#pragma unroll
  for (int z = 1; z < SK; z++) {
    float4 t = *(const float4*)(P + (size_t)z * MN + i4);
    s.x += t.x; s.y += t.y; s.z += t.z; s.w += t.w;
  }
  // decode blocked index -> (row, col): lane(6) q(6) wave(2) bx(2) by(3)
  const int lane0 = i4 & 63;
  const int q     = (i4 >> 6) & 63;
  const int wave  = (i4 >> 12) & 3;
  const int bx    = (i4 >> 14) & 3;
  const int by    = (i4 >> 16) & 7;
  const int rr = q & 3, j_ = (q >> 2) & 3, i_ = q >> 4;
  const int row = bx * 128 + (wave & 1) * 64 + i_ * 16 + (lane0 >> 4) * 4 + rr;
  const int col = by * 128 + (wave >> 1) * 64 + j_ * 16 + (lane0 & 15);
  float4 bv = *(const float4*)(bias + col);
  s.x += bv.x; s.y += bv.y; s.z += bv.z; s.w += bv.w;
  if (RELU) {
    s.x = fmaxf(s.x, 0.0f); s.y = fmaxf(s.y, 0.0f);
    s.z = fmaxf(s.z, 0.0f); s.w = fmaxf(s.w, 0.0f);
  }
  size_t o = (size_t)row * N + col;
  if (OUT16) {
    f16x4 ov;
    ov[0] = (half_t)s.x; ov[1] = (half_t)s.y; ov[2] = (half_t)s.z; ov[3] = (half_t)s.w;
    *(f16x4*)((half_t*)out + o) = ov;
  } else {
    *(float4*)((float*)out + o) = s;
  }
}

// ---------------- fp32 GEMM3: om(N,147) = h2(N,1024) @ w3(147,1024)^T + b3 ----------------
__global__ __launch_bounds__(192) void gemm_small(const float* __restrict__ h2,
                                                  const float* __restrict__ w3,
                                                  const float* __restrict__ b3,
                                                  float* __restrict__ om) {
  __shared__ float hs[FC];
  int n = blockIdx.x;
  for (int k = threadIdx.x; k < FC; k += 192) hs[k] = h2[(size_t)n * FC + k];
  __syncthreads();
  int j = threadIdx.x;
  if (j < 147) {
    float acc = b3[j];
    const float* wr = w3 + (size_t)j * FC;
    for (int k = 0; k < FC; k += 4) {
      float4 wv = *(const float4*)(wr + k);
      acc += hs[k] * wv.x + hs[k + 1] * wv.y + hs[k + 2] * wv.z + hs[k + 3] * wv.w;
    }
    om[n * 147 + j] = acc;
  }
}

extern "C" void kernel_launch(void* const* d_in, const int* in_sizes, int n_in,
                              void* d_out, int out_size, void* d_ws, size_t ws_size,
                              hipStream_t stream) {
  const float* feat = (const float*)d_in[0];
  const float* rois = (const float*)d_in[1];
  const float* w1 = (const float*)d_in[2];
  const float* b1 = (const float*)d_in[3];
  const float* w2 = (const float*)d_in[4];
  const float* b2 = (const float*)d_in[5];
  const float* w3 = (const float*)d_in[6];
  const float* b3 = (const float*)d_in[7];
  float* out = (float*)d_out;
  char* ws = (char*)d_ws;

  // workspace carve (~83.7 MB total)
  half_t* featT = (half_t*)ws;                        // 10,240,000 B
  half_t* xh    = (half_t*)(ws + 10240000);           // 12,845,056 B  (k = c*49+p)
  half_t* w1h   = (half_t*)(ws + 23085056);           // 25,690,112 B  (raw layout)
  half_t* w2h   = (half_t*)(ws + 48775168);           //  2,097,152 B
  half_t* h1    = (half_t*)(ws + 50872320);           //  1,048,576 B
  float*  h2    = (float*)(ws + 51920896);            //  2,097,152 B
  float*  omb   = (float*)(ws + 54018048);            //    301,056 B
  float*  part  = (float*)(ws + 54319104);            // 29,360,128 B

  const int MN = NROI * FC;  // 524288

  transpose_feat<<<dim3(313, 8, 2), dim3(32, 8), 0, stream>>>(feat, featT);
  convert_f32_f16<<<dim3(12544), dim3(256), 0, stream>>>(w1, w1h, FC * KDIM);
  convert_f32_f16<<<dim3(1024), dim3(256), 0, stream>>>(w2, w2h, FC * FC);
  pool_kernel<false><<<dim3(NROI), dim3(512), 0, stream>>>(featT, rois, nullptr, xh, nullptr);

  // GEMM1: (512x12544) @ (1024x12544)^T -> 128x128 tiles, SK=14, 448 blocks
  gemm_sk<14><<<dim3(4, 8, 14), dim3(256), 0, stream>>>(xh, w1h, part, NROI, FC, KDIM);
  reduce_blocked<true, true, 14><<<dim3(MN / 1024), dim3(256), 0, stream>>>(part, b1, (void*)h1, MN, FC);

  // GEMM2: (512x1024) @ (1024x1024)^T -> SK=8, 256 blocks
  gemm_sk<8><<<dim3(4, 8, 8), dim3(256), 0, stream>>>(h1, w2h, part, NROI, FC, FC);
  reduce_blocked<false, true, 8><<<dim3(MN / 1024), dim3(256), 0, stream>>>(part, b2, (void*)h2, MN, FC);

  gemm_small<<<dim3(NROI), dim3(192), 0, stream>>>(h2, w3, b3, omb);
  pool_kernel<true><<<dim3(NROI), dim3(512), 0, stream>>>(featT, rois, omb, nullptr, out);
}